// Round 7
// baseline (250.911 us; speedup 1.0000x reference)
//
#include <hip/hip_runtime.h>

// Problem constants (T=512, B=16 -> 8192 tokens), all tensors float32
#define NTOK 8192
#define CDIM 512
#define NB   8
#define RD   64
#define OD   512

// Fused kernel geometry: 512 blocks x 256 threads (4 waves), co-residency
// needs only 2 blocks/CU (LDS 53 KB/block, VGPR capped 256) -> safe margin.
#define NBLK  512
#define TPB_A 16                   // tokens per block in the phase-A part
#define XPAD  4                    // pad x rows to 516 f32: float4-aligned
#define XROW  (CDIM + XPAD)        // 516
#define XROW4 (XROW / 4)           // 129

typedef unsigned char u8;

__device__ __forceinline__ float4 f4add(float4 a, float4 b) {
    return make_float4(a.x + b.x, a.y + b.y, a.z + b.z, a.w + b.w);
}
// Exact expression shape of the verified kernels: ((ax*bx + ay*by) + az*bz) + aw*bw
__device__ __forceinline__ float dot4(float4 a, float4 b) {
    return a.x * b.x + a.y * b.y + a.z * b.z + a.w * b.w;
}

// ---------------------------------------------------------------------------
// Fused kernel. Rounds 0-6 established a ~52 us content-independent floor per
// dispatch (phaseA 52-58 us across 5 structural variants incl. zero-conflict
// LDS + scalar-x; phaseB ~47-53 us across 4 variants; real work by roofline
// is ~10-15 us each). Fusing pays the floor once. Structure:
//   phase A (verbatim r3 math): stage x, f64 logits -> q, ping-pong v-GEMM
//   issue phase-B weight loads (independent of phase A -> fly over barrier)
//   device-scope grid barrier (counter in ws, memset-0 by host each launch)
//   phase B (verbatim r3 math, 2 blocks/code, 256 outputs each)
// All floating-point sequences are bit-identical to the verified kernels.
// ---------------------------------------------------------------------------
__global__ __launch_bounds__(256, 2) void fused(
    const float* __restrict__ x, const float* __restrict__ map_w,
    const float* __restrict__ map_b, const float* __restrict__ w1,
    const float* __restrict__ w21, const float* __restrict__ w22,
    const float* __restrict__ pwB,
    u8* __restrict__ q_arr, float* __restrict__ v_arr,
    float* __restrict__ y, float* __restrict__ loss_out,
    int* __restrict__ bar)
{
    const int t    = threadIdx.x;
    const int bid  = blockIdx.x;
    const int tok0 = bid * TPB_A;

    __shared__ __align__(16) float xs[TPB_A * XROW];   // 33 KB
    __shared__ unsigned short list[NTOK];              // 16 KB
    __shared__ __align__(16) float vs[16 * RD];        // 4 KB
    __shared__ int cnt;

    // ================= phase A =================
    // ---- stage x tile (coalesced float4, padded LDS rows) ----
    const float4* xsrc = (const float4*)(x + (size_t)tok0 * CDIM);
    #pragma unroll
    for (int i = t; i < TPB_A * (CDIM / 4); i += 256) {
        int r = i >> 7, c = i & 127;                    // CDIM/4 = 128
        *((float4*)(xs + r * XROW) + c) = xsrc[i];
    }
    __syncthreads();

    // ---- logits (waves 0-1): one thread per (token,bit), f64 accumulation ----
    if (t < 128) {                                      // wave-uniform guard
        const int bit = t & 7, tk = t >> 3;             // tk in 0..15
        const float4* m4 = (const float4*)(map_w + (size_t)bit * CDIM);
        const float4* x4 = (const float4*)xs + tk * XROW4;
        double a0 = 0.0, a1 = 0.0;
        for (int j = 0; j < CDIM / 4; ++j) {
            float4 m = m4[j], xv = x4[j];
            a0 += (double)m.x * (double)xv.x + (double)m.y * (double)xv.y;
            a1 += (double)m.z * (double)xv.z + (double)m.w * (double)xv.w;
        }
        double k = a0 + a1 + (double)map_b[bit];
        unsigned long long m = __ballot(k > 0.0);
        const int lane = t & 63;
        if ((lane & 7) == 0) {
            int g = lane >> 3;                          // local token in wave
            q_arr[tok0 + tk] = (u8)((m >> (g * 8)) & 0xFFull);
        }
    }

    // ---- v: wave tg -> tokens tg*4..tg*4+3, lane r = w1 row, ping-pong ----
    {
        const int r  = t & 63;
        const int tg = t >> 6;                          // 0..3
        const float4* w4 = (const float4*)(w1 + (size_t)r * CDIM);
        const float4* xq = (const float4*)xs + (size_t)(tg * 4) * XROW4;
        float acc0 = 0.f, acc1 = 0.f, acc2 = 0.f, acc3 = 0.f;

#define CONSUME(WV, J) { const int jj = (J);                       \
        acc0 += dot4(WV, xq[jj]);                                  \
        acc1 += dot4(WV, xq[1 * XROW4 + jj]);                      \
        acc2 += dot4(WV, xq[2 * XROW4 + jj]);                      \
        acc3 += dot4(WV, xq[3 * XROW4 + jj]); }

        float4 A0 = w4[0], A1 = w4[1], A2 = w4[2], A3 = w4[3];
        float4 B0, B1, B2, B3;
        for (int b = 0; b < CDIM / 4; b += 8) {
            B0 = w4[b + 4]; B1 = w4[b + 5]; B2 = w4[b + 6]; B3 = w4[b + 7];
            CONSUME(A0, b)     CONSUME(A1, b + 1)
            CONSUME(A2, b + 2) CONSUME(A3, b + 3)
            if (b + 8 < CDIM / 4) {
                A0 = w4[b + 8]; A1 = w4[b + 9]; A2 = w4[b + 10]; A3 = w4[b + 11];
            }
            CONSUME(B0, b + 4) CONSUME(B1, b + 5)
            CONSUME(B2, b + 6) CONSUME(B3, b + 7)
        }
#undef CONSUME

        float* vo = v_arr + (size_t)(tok0 + tg * 4) * RD + r;   // coalesced
        vo[0 * RD] = acc0; vo[1 * RD] = acc1; vo[2 * RD] = acc2; vo[3 * RD] = acc3;
    }

    if (bid == 0 && t == 0) loss_out[0] = 0.0f;         // loss = 0

    // ======== phase-B weight loads: independent of phase A, issue early ====
    const int q    = bid >> 1;                          // code 0..255
    const int half = bid & 1;
    const int o    = half * 256 + t;                    // owned output
    const float4* pa = (const float4*)w21 + (size_t)q * (OD * RD / 4) + (size_t)o * (RD / 4);
    const float4* pb = (const float4*)w22 + (size_t)(255 - q) * (OD * RD / 4) + (size_t)o * (RD / 4);
    float4 a0 = pa[0],  a1 = pa[1],  a2 = pa[2],  a3 = pa[3],
           a4 = pa[4],  a5 = pa[5],  a6 = pa[6],  a7 = pa[7],
           a8 = pa[8],  a9 = pa[9],  a10 = pa[10], a11 = pa[11],
           a12 = pa[12], a13 = pa[13], a14 = pa[14], a15 = pa[15];
    float4 b0 = pb[0],  b1 = pb[1],  b2 = pb[2],  b3 = pb[3],
           b4 = pb[4],  b5 = pb[5],  b6 = pb[6],  b7 = pb[7],
           b8 = pb[8],  b9 = pb[9],  b10 = pb[10], b11 = pb[11],
           b12 = pb[12], b13 = pb[13], b14 = pb[14], b15 = pb[15];
    const float bias = pwB[o];

    // ================= grid barrier =================
    // counter zeroed by hipMemsetAsync before this kernel. Release fence ->
    // arrive -> spin (device-scope atomic reads, bounded) -> acquire fence.
    __syncthreads();
    if (t == 0) {
        __threadfence();                                // release q/v writes
        atomicAdd(bar, 1);
        int guard = 0;
        while (atomicAdd(bar, 0) < NBLK) {
            __builtin_amdgcn_s_sleep(8);
            if (++guard > (1 << 22)) break;             // safety valve: no hang
        }
        __threadfence();                                // acquire
    }
    __syncthreads();

    // ================= phase B =================
    // ---- scan q_arr (registers), LDS atomic append ----
    if (t == 0) cnt = 0;
    __syncthreads();
    const uint4* qa = (const uint4*)q_arr;
    uint4 qv0 = qa[t], qv1 = qa[t + 256];
#define CHK(WORD, SB, OFF) { unsigned uw = (WORD); \
    if ((int)(uw & 0xFFu)         == q) list[atomicAdd(&cnt, 1)] = (unsigned short)((SB) + (OFF));     \
    if ((int)((uw >> 8)  & 0xFFu) == q) list[atomicAdd(&cnt, 1)] = (unsigned short)((SB) + (OFF) + 1); \
    if ((int)((uw >> 16) & 0xFFu) == q) list[atomicAdd(&cnt, 1)] = (unsigned short)((SB) + (OFF) + 2); \
    if ((int)(uw >> 24)           == q) list[atomicAdd(&cnt, 1)] = (unsigned short)((SB) + (OFF) + 3); }
    { int sb = t * 16;          CHK(qv0.x, sb, 0) CHK(qv0.y, sb, 4) CHK(qv0.z, sb, 8) CHK(qv0.w, sb, 12) }
    { int sb = (t + 256) * 16;  CHK(qv1.x, sb, 0) CHK(qv1.y, sb, 4) CHK(qv1.z, sb, 8) CHK(qv1.w, sb, 12) }
#undef CHK
    __syncthreads();
    const int n = cnt;
    if (n == 0) return;                                 // uniform exit

    // ---- fuse (w21 + w22) into 16 named registers ----
    float4 f0 = f4add(a0, b0),  f1 = f4add(a1, b1),  f2 = f4add(a2, b2),  f3 = f4add(a3, b3),
           f4 = f4add(a4, b4),  f5 = f4add(a5, b5),  f6 = f4add(a6, b6),  f7 = f4add(a7, b7),
           f8 = f4add(a8, b8),  f9 = f4add(a9, b9),  f10 = f4add(a10, b10), f11 = f4add(a11, b11),
           f12 = f4add(a12, b12), f13 = f4add(a13, b13), f14 = f4add(a14, b14), f15 = f4add(a15, b15);

    // ---- stream tokens in batches of 16, token pairs (2 acc chains) ----
    const float4* v4 = (const float4*)v_arr;
    for (int base = 0; base < n; base += 16) {
        const int nb = min(16, n - base);
        if (t < nb * 16)                                // 16 tok x 16 float4
            ((float4*)vs)[t] = v4[(size_t)list[base + (t >> 4)] * (RD / 4) + (t & 15)];
        __syncthreads();
        int i = 0;
        for (; i + 2 <= nb; i += 2) {
            const float4* p0 = (const float4*)vs + (size_t)i * 16;
            const float4* p1 = p0 + 16;
            float acc0 = bias, acc1 = bias;
#define STEP(J, W) { float4 u0 = p0[J], u1 = p1[J]; \
            acc0 += W.x * u0.x + W.y * u0.y + W.z * u0.z + W.w * u0.w; \
            acc1 += W.x * u1.x + W.y * u1.y + W.z * u1.z + W.w * u1.w; }
            STEP(0, f0)  STEP(1, f1)  STEP(2, f2)  STEP(3, f3)
            STEP(4, f4)  STEP(5, f5)  STEP(6, f6)  STEP(7, f7)
            STEP(8, f8)  STEP(9, f9)  STEP(10, f10) STEP(11, f11)
            STEP(12, f12) STEP(13, f13) STEP(14, f14) STEP(15, f15)
#undef STEP
            y[(size_t)list[base + i]     * OD + o] = acc0;
            y[(size_t)list[base + i + 1] * OD + o] = acc1;
        }
        if (i < nb) {                                   // odd tail
            const float4* p0 = (const float4*)vs + (size_t)i * 16;
            float acc0 = bias;
#define STEP1(J, W) { float4 u0 = p0[J]; \
            acc0 += W.x * u0.x + W.y * u0.y + W.z * u0.z + W.w * u0.w; }
            STEP1(0, f0)  STEP1(1, f1)  STEP1(2, f2)  STEP1(3, f3)
            STEP1(4, f4)  STEP1(5, f5)  STEP1(6, f6)  STEP1(7, f7)
            STEP1(8, f8)  STEP1(9, f9)  STEP1(10, f10) STEP1(11, f11)
            STEP1(12, f12) STEP1(13, f13) STEP1(14, f14) STEP1(15, f15)
#undef STEP1
            y[(size_t)list[base + i] * OD + o] = acc0;
        }
        __syncthreads();
    }
}

// ---------------------------------------------------------------------------
// Fallback (ws too small): workspace-free, one block per token.
// ---------------------------------------------------------------------------
__global__ __launch_bounds__(256) void mono(
    const float* __restrict__ x, const float* __restrict__ map_w,
    const float* __restrict__ map_b, const float* __restrict__ w1,
    const float* __restrict__ w21, const float* __restrict__ w22,
    const float* __restrict__ pwB, float* __restrict__ y)
{
    const int tok = blockIdx.x;
    const int t   = threadIdx.x;
    __shared__ float xsh[CDIM];
    __shared__ float vsh[RD];
    __shared__ int qsh;

    if (t == 0) qsh = 0;
    for (int i = t; i < CDIM; i += 256) xsh[i] = x[(size_t)tok * CDIM + i];
    __syncthreads();

    if (t < NB) {
        double a = 0.0;
        const float* mrow = map_w + (size_t)t * CDIM;
        for (int j = 0; j < CDIM; ++j) a += (double)mrow[j] * (double)xsh[j];
        a += (double)map_b[t];
        if (a > 0.0) atomicOr(&qsh, 1 << t);
    }
    if (t < RD) {
        const float* wrow = w1 + (size_t)t * CDIM;
        float acc = 0.f;
        for (int j = 0; j < CDIM; ++j) acc += wrow[j] * xsh[j];
        vsh[t] = acc;
    }
    __syncthreads();

    const int q = qsh;
    for (int o = t; o < OD; o += 256) {
        const float* pa = w21 + (size_t)q * (OD * RD) + (size_t)o * RD;
        const float* pb = w22 + (size_t)(255 - q) * (OD * RD) + (size_t)o * RD;
        float acc = pwB[o];
        for (int r = 0; r < RD; ++r) acc += (pa[r] + pb[r]) * vsh[r];
        y[(size_t)tok * OD + o] = acc;
    }
    if (tok == 0 && t == 0) y[(size_t)NTOK * OD] = 0.0f;
}

extern "C" void kernel_launch(void* const* d_in, const int* in_sizes, int n_in,
                              void* d_out, int out_size, void* d_ws, size_t ws_size,
                              hipStream_t stream) {
    const float* x     = (const float*)d_in[0];
    // d_in[1] = key: unused by the forward pass
    const float* map_w = (const float*)d_in[2];
    const float* map_b = (const float*)d_in[3];
    const float* w1    = (const float*)d_in[4];
    const float* w21   = (const float*)d_in[5];
    const float* w22   = (const float*)d_in[6];
    const float* pwB   = (const float*)d_in[7];
    float* out = (float*)d_out;

    const size_t vq_bytes = (size_t)NTOK + (size_t)NTOK * RD * sizeof(float); // 8KB + 2MB
    const size_t need = vq_bytes + 64;                 // + barrier counter
    if (ws_size >= need) {
        u8*    q_ws = (u8*)d_ws;
        float* v_ws = (float*)((char*)d_ws + NTOK);
        int*   bar  = (int*)((char*)d_ws + vq_bytes);
        hipMemsetAsync(bar, 0, sizeof(int), stream);   // graph-capturable
        fused<<<NBLK, 256, 0, stream>>>(x, map_w, map_b, w1, w21, w22, pwB,
                                        q_ws, v_ws, out,
                                        out + (size_t)NTOK * OD, bar);
    } else {
        mono<<<NTOK, 256, 0, stream>>>(x, map_w, map_b, w1, w21, w22, pwB, out);
    }
}